// Round 15
// baseline (183.308 us; speedup 1.0000x reference)
//
#include <hip/hip_runtime.h>
#include <hip/hip_bf16.h>

// Problem constants
#define B_   32
#define N_   2048
#define E_   768
#define OUT_ 384
#define HID_ 16
constexpr int ROWS   = B_ * N_;      // 65536
constexpr int TILE_M = 16;           // rows per tile
constexpr int TPB    = 8;            // tiles per block (persistent)
constexpr int NT     = OUT_ / 16;    // 24 N-tiles of local GEMM
constexpr int KT_L   = 6;            // 6 K-steps (local, K=192)
constexpr int KT_G   = 24;           // 24 K-steps (gate, K=768)
constexpr int S_AL   = 200;          // al row stride in shorts (400B)
constexpr int S_PL   = 392;          // pooled row stride in shorts
constexpr int XS_W   = 772;          // xs row stride in floats (3088B)

typedef __attribute__((ext_vector_type(8))) short bf16x8;
typedef __attribute__((ext_vector_type(4))) float f32x4;

__device__ __forceinline__ short f2bf(float f) {
  __hip_bfloat16 h = __float2bfloat16(f);
  return __builtin_bit_cast(short, h);
}
__device__ __forceinline__ float bf2f(short s) {
  union { unsigned u; float f; } v; v.u = ((unsigned)(unsigned short)s) << 16;
  return v.f;
}

// deep async L2 load: issued where placed, cannot be sunk by the compiler
__device__ __forceinline__ void gload_frag(bf16x8& d, const short* a) {
  asm volatile("global_load_dwordx4 %0, %1, off" : "=&v"(d) : "v"(a));
}
#define WAITV(n) do { asm volatile("s_waitcnt vmcnt(" #n ")" ::: "memory"); \
                      __builtin_amdgcn_sched_barrier(0); } while (0)

// Abramowitz-Stegun 7.1.26, |err| <= 1.5e-7, branch-free
__device__ __forceinline__ float fast_erf(float x) {
  const float ax = __builtin_fabsf(x);
  const float t  = __builtin_amdgcn_rcpf(__builtin_fmaf(0.3275911f, ax, 1.0f));
  float p = __builtin_fmaf(1.061405429f, t, -1.453152027f);
  p = __builtin_fmaf(p, t, 1.421413741f);
  p = __builtin_fmaf(p, t, -0.284496736f);
  p = __builtin_fmaf(p, t, 0.254829592f);
  const float e = __expf(-ax * ax);
  const float y = __builtin_fmaf(-p * t, e, 1.0f);
  return __builtin_copysignf(y, x);
}
__device__ __forceinline__ float gelu(float v) {
  return 0.5f * v * (1.0f + fast_erf(v * 0.70710678118654752f));
}

// ---------------- pre-pass: build bf16 MFMA B-fragments in workspace ----------------
__global__ void prep_kernel(const float* __restrict__ w_l, const float* __restrict__ w_g1,
                            short* __restrict__ wsL, short* __restrict__ wsG) {
  int t = blockIdx.x * blockDim.x + threadIdx.x;
  int wave = t >> 6, ln = t & 63;
  int kg = ln >> 4, c16 = ln & 15;
  if (wave < NT * KT_L) {
    int n = wave / KT_L, ks = wave % KT_L;
    bf16x8 v;
#pragma unroll
    for (int j = 0; j < 8; ++j) {
      int k = ks * 32 + kg * 8 + j;
      v[j] = f2bf(w_l[k * OUT_ + n * 16 + c16]);
    }
    *reinterpret_cast<bf16x8*>(&wsL[(size_t)(wave * 64 + ln) * 8]) = v;
  } else if (wave < NT * KT_L + KT_G) {
    int ks = wave - NT * KT_L;
    bf16x8 v;
#pragma unroll
    for (int j = 0; j < 8; ++j) {
      int k = ks * 32 + kg * 8 + j;
      v[j] = f2bf(w_g1[k * HID_ + c16]);
    }
    *reinterpret_cast<bf16x8*>(&wsG[(size_t)(ks * 64 + ln) * 8]) = v;
  }
}

// ---------------- main fused kernel: 256 threads = 4 waves, persistent over 8 tiles ----------------
// Stage issued AFTER the wsL frag burst so the counted-vmcnt ladder never waits on it.
// Stage is issued EVERY iteration (clamped index) so the ladder counts are invariant.
template <bool USE_WS>
__global__ __launch_bounds__(256, 2)
void spectre_kernel(const float* __restrict__ x,
                    const float* __restrict__ w_g1, const float* __restrict__ b_g1,
                    const float* __restrict__ ln_g_w, const float* __restrict__ ln_g_b,
                    const float* __restrict__ w_g2, const float* __restrict__ b_g2,
                    const float* __restrict__ w_l, const float* __restrict__ b_l,
                    const float* __restrict__ ln_l_w, const float* __restrict__ ln_l_b,
                    const short* __restrict__ wsL, const short* __restrict__ wsG,
                    float* __restrict__ out) {
  __shared__ float xs[TILE_M][XS_W];     // 49408 B: x tile f32
  __shared__ short al[TILE_M * S_AL];    // 6400 B : local A (x[..., ::4] bf16)
  __shared__ short pl[TILE_M * S_PL];    // 12544 B: pooled (bf16)
  __shared__ float red2[4][16][17];      // 4352 B : gate partials per wave
  __shared__ float reds[4][16][2];       // 512 B  : local LN partials per wave

  const int tid = threadIdx.x;
  const int wv  = tid >> 6;        // wave 0..3
  const int ln  = tid & 63;        // lane
  const int kg  = ln >> 4;         // k-group / D-row group
  const int l15 = ln & 15;         // A-row / D-col

  const float bg  = b_g1[l15];
  const float lgw = ln_g_w[l15];
  const float lgb = ln_g_b[l15];
  const float wg2 = w_g2[l15];
  const float bg2 = b_g2[0];
  float blv[6], lwv[6], lbv[6];
#pragma unroll
  for (int j = 0; j < 6; ++j) {
    const int col = (wv * 6 + j) * 16 + l15;
    blv[j] = b_l[col];
    lwv[j] = ln_l_w[col];
    lbv[j] = ln_l_b[col];
  }
  const short* wlp = USE_WS ? (wsL + ((size_t)(wv * 6) * KT_L * 64 + ln) * 8) : nullptr;

  // ---- stage helper: 12 global_load_lds per wave (4 rows x 3 KB) ----
  auto stage = [&](int t) {
    const float* src = x + (size_t)(blockIdx.x * TPB + t) * TILE_M * E_;
#pragma unroll
    for (int rr = 0; rr < 4; ++rr) {
      const int row = wv * 4 + rr;
#pragma unroll
      for (int c = 0; c < 3; ++c) {
        __builtin_amdgcn_global_load_lds(
            (const __attribute__((address_space(1))) void*)(src + row * E_ + c * 256 + ln * 4),
            (__attribute__((address_space(3))) void*)(&xs[row][c * 256]),
            16, 0, 0);
      }
    }
  };

  // ---- prologue: stage tile 0 ----
  stage(0);
  asm volatile("s_waitcnt vmcnt(0)" ::: "memory");
  __syncthreads();

#pragma unroll 1
  for (int t = 0; t < TPB; ++t) {
    const size_t rowg0 = (size_t)(blockIdx.x * TPB + t) * TILE_M;

    // ---- gate GEMM partial (wave wv: K-steps [6wv,6wv+6)); al/pl extracted inline ----
    f32x4 accg = {0.f, 0.f, 0.f, 0.f};
#pragma unroll
    for (int i = 0; i < 6; ++i) {
      const int ks = wv * 6 + i;
      const float4 u0 = *reinterpret_cast<const float4*>(&xs[l15][ks * 32 + kg * 8]);
      const float4 u1 = *reinterpret_cast<const float4*>(&xs[l15][ks * 32 + kg * 8 + 4]);
      short2 lv;
      lv.x = f2bf(u0.x);
      lv.y = f2bf(u1.x);
      *reinterpret_cast<short2*>(&al[l15 * S_AL + 8 * ks + 2 * kg]) = lv;
      short4 pv;
      pv.x = f2bf(0.5f * (u0.x + u0.y));
      pv.y = f2bf(0.5f * (u0.z + u0.w));
      pv.z = f2bf(0.5f * (u1.x + u1.y));
      pv.w = f2bf(0.5f * (u1.z + u1.w));
      *reinterpret_cast<short4*>(&pl[l15 * S_PL + ks * 16 + kg * 4]) = pv;
      const bf16x8 a = { lv.x, f2bf(u0.y), f2bf(u0.z), f2bf(u0.w),
                         lv.y, f2bf(u1.y), f2bf(u1.z), f2bf(u1.w) };
      bf16x8 b;
      if constexpr (USE_WS) {
        b = *reinterpret_cast<const bf16x8*>(&wsG[(ks * 64 + ln) * 8]);
      } else {
#pragma unroll
        for (int j = 0; j < 8; ++j) b[j] = f2bf(w_g1[(ks * 32 + kg * 8 + j) * HID_ + l15]);
      }
      accg = __builtin_amdgcn_mfma_f32_16x16x32_bf16(a, b, accg, 0, 0, 0);
    }
#pragma unroll
    for (int r = 0; r < 4; ++r) red2[wv][kg * 4 + r][l15] = accg[r];

    __syncthreads();   // B1: xs consumed; al/pl/red2 visible

    f32x4 acc[6];
#pragma unroll
    for (int j = 0; j < 6; ++j) acc[j] = (f32x4){0.f, 0.f, 0.f, 0.f};

    if constexpr (USE_WS) {
      // ---- burst: ALL 36 wsL frag loads first, THEN the 12 stage loads ----
      bf16x8 fg[36];
#pragma unroll
      for (int ks = 0; ks < 6; ++ks)
#pragma unroll
        for (int j = 0; j < 6; ++j)
          gload_frag(fg[ks * 6 + j], wlp + (j * 6 + ks) * 512);
      __builtin_amdgcn_sched_barrier(0);
      // Always issue the stage (clamped) so the vmcnt ladder counts are the same
      // in EVERY iteration; last tile re-stages itself (L2-hot, xs is dead).
      stage(t + 1 < TPB ? t + 1 : t);
      __builtin_amdgcn_sched_barrier(0);

      // ---- gate finalize under the L2 latency of group 0 ----
      float gf[4];
#pragma unroll
      for (int r = 0; r < 4; ++r) {
        const int row = kg * 4 + r;
        const float y = red2[0][row][l15] + red2[1][row][l15] +
                        red2[2][row][l15] + red2[3][row][l15] + bg;
        float s = y, q = y * y;
#pragma unroll
        for (int m = 1; m < 16; m <<= 1) {
          s += __shfl_xor(s, m);
          q += __shfl_xor(q, m);
        }
        const float mean = s * (1.f / 16.f);
        const float var  = q * (1.f / 16.f) - mean * mean;
        const float rstd = rsqrtf(var + 1e-5f);
        const float vn = (y - mean) * rstd * lgw + lgb;
        float ps = gelu(vn) * wg2;
#pragma unroll
        for (int m = 1; m < 16; m <<= 1) ps += __shfl_xor(ps, m);
        gf[r] = ps + bg2;
      }

      // ---- ladder: each group waits ONLY its frags; stage rides behind ----
      bf16x8 aLc = *reinterpret_cast<const bf16x8*>(&al[l15 * S_AL + kg * 8]);
      bf16x8 aLn = *reinterpret_cast<const bf16x8*>(&al[l15 * S_AL + 32 + kg * 8]);
      WAITV(42);
#pragma unroll
      for (int j = 0; j < 6; ++j)
        acc[j] = __builtin_amdgcn_mfma_f32_16x16x32_bf16(aLc, fg[0 * 6 + j], acc[j], 0, 0, 0);
      aLc = aLn; aLn = *reinterpret_cast<const bf16x8*>(&al[l15 * S_AL + 64 + kg * 8]);
      WAITV(36);
#pragma unroll
      for (int j = 0; j < 6; ++j)
        acc[j] = __builtin_amdgcn_mfma_f32_16x16x32_bf16(aLc, fg[1 * 6 + j], acc[j], 0, 0, 0);
      aLc = aLn; aLn = *reinterpret_cast<const bf16x8*>(&al[l15 * S_AL + 96 + kg * 8]);
      WAITV(30);
#pragma unroll
      for (int j = 0; j < 6; ++j)
        acc[j] = __builtin_amdgcn_mfma_f32_16x16x32_bf16(aLc, fg[2 * 6 + j], acc[j], 0, 0, 0);
      aLc = aLn; aLn = *reinterpret_cast<const bf16x8*>(&al[l15 * S_AL + 128 + kg * 8]);
      WAITV(24);
#pragma unroll
      for (int j = 0; j < 6; ++j)
        acc[j] = __builtin_amdgcn_mfma_f32_16x16x32_bf16(aLc, fg[3 * 6 + j], acc[j], 0, 0, 0);
      aLc = aLn; aLn = *reinterpret_cast<const bf16x8*>(&al[l15 * S_AL + 160 + kg * 8]);
      WAITV(18);
#pragma unroll
      for (int j = 0; j < 6; ++j)
        acc[j] = __builtin_amdgcn_mfma_f32_16x16x32_bf16(aLc, fg[4 * 6 + j], acc[j], 0, 0, 0);
      aLc = aLn;
      WAITV(12);
#pragma unroll
      for (int j = 0; j < 6; ++j)
        acc[j] = __builtin_amdgcn_mfma_f32_16x16x32_bf16(aLc, fg[5 * 6 + j], acc[j], 0, 0, 0);
      WAITV(0);   // stage drained here (HBM stream rode behind the whole GEMM)

      // ---- LN stats + cross-wave combine ----
      float s1[4] = {0.f, 0.f, 0.f, 0.f}, s2[4] = {0.f, 0.f, 0.f, 0.f};
#pragma unroll
      for (int j = 0; j < 6; ++j) {
#pragma unroll
        for (int r = 0; r < 4; ++r) {
          const float v = acc[j][r] + blv[j];
          acc[j][r] = v;
          s1[r] += v;
          s2[r] += v * v;
        }
      }
#pragma unroll
      for (int m = 1; m < 16; m <<= 1) {
#pragma unroll
        for (int r = 0; r < 4; ++r) {
          s1[r] += __shfl_xor(s1[r], m);
          s2[r] += __shfl_xor(s2[r], m);
        }
      }
      if (l15 == 0) {
#pragma unroll
        for (int r = 0; r < 4; ++r) {
          reds[wv][kg * 4 + r][0] = s1[r];
          reds[wv][kg * 4 + r][1] = s2[r];
        }
      }
      __syncthreads();   // B2

      float meanr[4], rstdr[4];
#pragma unroll
      for (int r = 0; r < 4; ++r) {
        const int row = kg * 4 + r;
        const float t1 = reds[0][row][0] + reds[1][row][0] + reds[2][row][0] + reds[3][row][0];
        const float t2 = reds[0][row][1] + reds[1][row][1] + reds[2][row][1] + reds[3][row][1];
        meanr[r] = t1 * (1.f / 384.f);
        const float var = t2 * (1.f / 384.f) - meanr[r] * meanr[r];
        rstdr[r] = rsqrtf(var + 1e-5f);
      }
#pragma unroll
      for (int j = 0; j < 6; ++j) {
        const int col = (wv * 6 + j) * 16 + l15;
#pragma unroll
        for (int r = 0; r < 4; ++r) {
          const int row = kg * 4 + r;
          const float pooled = bf2f(pl[row * S_PL + col]);
          const float vn = (acc[j][r] - meanr[r]) * rstdr[r] * lwv[j] + lbv[j];
          out[(rowg0 + row) * OUT_ + col] = gelu(vn) + gf[r] + pooled;
        }
      }
      __syncthreads();   // B3: al/pl consumed

    } else {
      // fallback (no workspace): simple serial version
      if (t + 1 < TPB) stage(t + 1);
      float gf[4];
#pragma unroll
      for (int r = 0; r < 4; ++r) {
        const int row = kg * 4 + r;
        const float y = red2[0][row][l15] + red2[1][row][l15] +
                        red2[2][row][l15] + red2[3][row][l15] + bg;
        float s = y, q = y * y;
#pragma unroll
        for (int m = 1; m < 16; m <<= 1) { s += __shfl_xor(s, m); q += __shfl_xor(q, m); }
        const float mean = s * (1.f / 16.f);
        const float var  = q * (1.f / 16.f) - mean * mean;
        const float rstd = rsqrtf(var + 1e-5f);
        const float vn = (y - mean) * rstd * lgw + lgb;
        float ps = gelu(vn) * wg2;
#pragma unroll
        for (int m = 1; m < 16; m <<= 1) ps += __shfl_xor(ps, m);
        gf[r] = ps + bg2;
      }
#pragma unroll
      for (int ks = 0; ks < KT_L; ++ks) {
        const bf16x8 aL = *reinterpret_cast<const bf16x8*>(&al[l15 * S_AL + ks * 32 + kg * 8]);
#pragma unroll
        for (int j = 0; j < 6; ++j) {
          const int ng = wv * 6 + j;
          bf16x8 b;
#pragma unroll
          for (int jj = 0; jj < 8; ++jj)
            b[jj] = f2bf(w_l[(ks * 32 + kg * 8 + jj) * OUT_ + ng * 16 + l15]);
          acc[j] = __builtin_amdgcn_mfma_f32_16x16x32_bf16(aL, b, acc[j], 0, 0, 0);
        }
      }
      asm volatile("s_waitcnt vmcnt(0)" ::: "memory");
      __builtin_amdgcn_sched_barrier(0);
      float s1[4] = {0.f, 0.f, 0.f, 0.f}, s2[4] = {0.f, 0.f, 0.f, 0.f};
#pragma unroll
      for (int j = 0; j < 6; ++j) {
#pragma unroll
        for (int r = 0; r < 4; ++r) {
          const float v = acc[j][r] + blv[j];
          acc[j][r] = v;
          s1[r] += v;
          s2[r] += v * v;
        }
      }
#pragma unroll
      for (int m = 1; m < 16; m <<= 1) {
#pragma unroll
        for (int r = 0; r < 4; ++r) {
          s1[r] += __shfl_xor(s1[r], m);
          s2[r] += __shfl_xor(s2[r], m);
        }
      }
      if (l15 == 0) {
#pragma unroll
        for (int r = 0; r < 4; ++r) {
          reds[wv][kg * 4 + r][0] = s1[r];
          reds[wv][kg * 4 + r][1] = s2[r];
        }
      }
      __syncthreads();
      float meanr[4], rstdr[4];
#pragma unroll
      for (int r = 0; r < 4; ++r) {
        const int row = kg * 4 + r;
        const float t1 = reds[0][row][0] + reds[1][row][0] + reds[2][row][0] + reds[3][row][0];
        const float t2 = reds[0][row][1] + reds[1][row][1] + reds[2][row][1] + reds[3][row][1];
        meanr[r] = t1 * (1.f / 384.f);
        const float var = t2 * (1.f / 384.f) - meanr[r] * meanr[r];
        rstdr[r] = rsqrtf(var + 1e-5f);
      }
#pragma unroll
      for (int j = 0; j < 6; ++j) {
        const int col = (wv * 6 + j) * 16 + l15;
#pragma unroll
        for (int r = 0; r < 4; ++r) {
          const int row = kg * 4 + r;
          const float pooled = bf2f(pl[row * S_PL + col]);
          const float vn = (acc[j][r] - meanr[r]) * rstdr[r] * lwv[j] + lbv[j];
          out[(rowg0 + row) * OUT_ + col] = gelu(vn) + gf[r] + pooled;
        }
      }
      __syncthreads();
    }
  }
}

// ---------------- launch ----------------
extern "C" void kernel_launch(void* const* d_in, const int* in_sizes, int n_in,
                              void* d_out, int out_size, void* d_ws, size_t ws_size,
                              hipStream_t stream) {
  (void)in_sizes; (void)n_in; (void)out_size;
  const float* x      = (const float*)d_in[0];
  const float* w_g1   = (const float*)d_in[1];
  const float* b_g1   = (const float*)d_in[2];
  const float* ln_g_w = (const float*)d_in[3];
  const float* ln_g_b = (const float*)d_in[4];
  const float* w_g2   = (const float*)d_in[5];
  const float* b_g2   = (const float*)d_in[6];
  const float* w_l    = (const float*)d_in[7];
  const float* b_l    = (const float*)d_in[8];
  const float* ln_l_w = (const float*)d_in[9];
  const float* ln_l_b = (const float*)d_in[10];
  float* out = (float*)d_out;

  const size_t needL = (size_t)NT * KT_L * 64 * 8;   // shorts
  const size_t needG = (size_t)KT_G * 64 * 8;        // shorts
  const bool use_ws = ws_size >= (needL + needG) * sizeof(short);

  short* wsL = (short*)d_ws;
  short* wsG = wsL + needL;

  const int grid = ROWS / (TILE_M * TPB);   // 512
  if (use_ws) {
    prep_kernel<<<(NT * KT_L + KT_G) * 64 / 256, 256, 0, stream>>>(w_l, w_g1, wsL, wsG);
    spectre_kernel<true><<<grid, 256, 0, stream>>>(x, w_g1, b_g1, ln_g_w, ln_g_b, w_g2, b_g2,
                                                   w_l, b_l, ln_l_w, ln_l_b, wsL, wsG, out);
  } else {
    spectre_kernel<false><<<grid, 256, 0, stream>>>(x, w_g1, b_g1, ln_g_w, ln_g_b, w_g2, b_g2,
                                                    w_l, b_l, ln_l_w, ln_l_b, nullptr, nullptr, out);
  }
}

// Round 16
// 113.960 us; speedup vs baseline: 1.6085x; 1.6085x over previous
//
#include <hip/hip_runtime.h>
#include <hip/hip_bf16.h>

// Problem constants
#define B_   32
#define N_   2048
#define E_   768
#define OUT_ 384
#define HID_ 16
constexpr int ROWS   = B_ * N_;      // 65536
constexpr int TILE_M = 16;           // rows per tile
constexpr int TPB    = 8;            // tiles per block (persistent)
constexpr int NT     = OUT_ / 16;    // 24 N-tiles of local GEMM
constexpr int KT_L   = 6;            // 6 K-steps (local, K=192)
constexpr int KT_G   = 24;           // 24 K-steps (gate, K=768)
constexpr int S_AL   = 200;          // al row stride in shorts (400B)
constexpr int S_PL   = 392;          // pooled row stride in shorts
constexpr int XS_W   = 772;          // xs row stride in floats (3088B)

typedef __attribute__((ext_vector_type(8))) short bf16x8;
typedef __attribute__((ext_vector_type(4))) float f32x4;

__device__ __forceinline__ short f2bf(float f) {
  __hip_bfloat16 h = __float2bfloat16(f);
  return __builtin_bit_cast(short, h);
}
__device__ __forceinline__ float bf2f(short s) {
  union { unsigned u; float f; } v; v.u = ((unsigned)(unsigned short)s) << 16;
  return v.f;
}

// deep async L2 load: issued where placed, cannot be sunk by the compiler
__device__ __forceinline__ void gload_frag(bf16x8& d, const short* a) {
  asm volatile("global_load_dwordx4 %0, %1, off" : "=&v"(d) : "v"(a));
}
#define WAITV(n) do { asm volatile("s_waitcnt vmcnt(" #n ")" ::: "memory"); \
                      __builtin_amdgcn_sched_barrier(0); } while (0)

// Abramowitz-Stegun 7.1.26, |err| <= 1.5e-7, branch-free
__device__ __forceinline__ float fast_erf(float x) {
  const float ax = __builtin_fabsf(x);
  const float t  = __builtin_amdgcn_rcpf(__builtin_fmaf(0.3275911f, ax, 1.0f));
  float p = __builtin_fmaf(1.061405429f, t, -1.453152027f);
  p = __builtin_fmaf(p, t, 1.421413741f);
  p = __builtin_fmaf(p, t, -0.284496736f);
  p = __builtin_fmaf(p, t, 0.254829592f);
  const float e = __expf(-ax * ax);
  const float y = __builtin_fmaf(-p * t, e, 1.0f);
  return __builtin_copysignf(y, x);
}
__device__ __forceinline__ float gelu(float v) {
  return 0.5f * v * (1.0f + fast_erf(v * 0.70710678118654752f));
}

// ---------------- pre-pass: build bf16 MFMA B-fragments in workspace ----------------
__global__ void prep_kernel(const float* __restrict__ w_l, const float* __restrict__ w_g1,
                            short* __restrict__ wsL, short* __restrict__ wsG) {
  int t = blockIdx.x * blockDim.x + threadIdx.x;
  int wave = t >> 6, ln = t & 63;
  int kg = ln >> 4, c16 = ln & 15;
  if (wave < NT * KT_L) {
    int n = wave / KT_L, ks = wave % KT_L;
    bf16x8 v;
#pragma unroll
    for (int j = 0; j < 8; ++j) {
      int k = ks * 32 + kg * 8 + j;
      v[j] = f2bf(w_l[k * OUT_ + n * 16 + c16]);
    }
    *reinterpret_cast<bf16x8*>(&wsL[(size_t)(wave * 64 + ln) * 8]) = v;
  } else if (wave < NT * KT_L + KT_G) {
    int ks = wave - NT * KT_L;
    bf16x8 v;
#pragma unroll
    for (int j = 0; j < 8; ++j) {
      int k = ks * 32 + kg * 8 + j;
      v[j] = f2bf(w_g1[k * HID_ + c16]);
    }
    *reinterpret_cast<bf16x8*>(&wsG[(size_t)(ks * 64 + ln) * 8]) = v;
  }
}

// ---------------- main fused kernel: 256 threads = 4 waves, persistent over 8 tiles ----------------
// Stage issued AFTER the wsL frag burst so the counted-vmcnt ladder never waits on it.
// __launch_bounds__(256,1): VGPR cap 512 so the 36-fragment burst (144 VGPRs) does NOT spill.
template <bool USE_WS>
__global__ __launch_bounds__(256, 1)
void spectre_kernel(const float* __restrict__ x,
                    const float* __restrict__ w_g1, const float* __restrict__ b_g1,
                    const float* __restrict__ ln_g_w, const float* __restrict__ ln_g_b,
                    const float* __restrict__ w_g2, const float* __restrict__ b_g2,
                    const float* __restrict__ w_l, const float* __restrict__ b_l,
                    const float* __restrict__ ln_l_w, const float* __restrict__ ln_l_b,
                    const short* __restrict__ wsL, const short* __restrict__ wsG,
                    float* __restrict__ out) {
  __shared__ float xs[TILE_M][XS_W];     // 49408 B: x tile f32
  __shared__ short al[TILE_M * S_AL];    // 6400 B : local A (x[..., ::4] bf16)
  __shared__ short pl[TILE_M * S_PL];    // 12544 B: pooled (bf16)
  __shared__ float red2[4][16][17];      // 4352 B : gate partials per wave
  __shared__ float reds[4][16][2];       // 512 B  : local LN partials per wave

  const int tid = threadIdx.x;
  const int wv  = tid >> 6;        // wave 0..3
  const int ln  = tid & 63;        // lane
  const int kg  = ln >> 4;         // k-group / D-row group
  const int l15 = ln & 15;         // A-row / D-col

  const float bg  = b_g1[l15];
  const float lgw = ln_g_w[l15];
  const float lgb = ln_g_b[l15];
  const float wg2 = w_g2[l15];
  const float bg2 = b_g2[0];
  float blv[6], lwv[6], lbv[6];
#pragma unroll
  for (int j = 0; j < 6; ++j) {
    const int col = (wv * 6 + j) * 16 + l15;
    blv[j] = b_l[col];
    lwv[j] = ln_l_w[col];
    lbv[j] = ln_l_b[col];
  }
  const short* wlp = USE_WS ? (wsL + ((size_t)(wv * 6) * KT_L * 64 + ln) * 8) : nullptr;

  // ---- stage helper: 12 global_load_lds per wave (4 rows x 3 KB) ----
  auto stage = [&](int t) {
    const float* src = x + (size_t)(blockIdx.x * TPB + t) * TILE_M * E_;
#pragma unroll
    for (int rr = 0; rr < 4; ++rr) {
      const int row = wv * 4 + rr;
#pragma unroll
      for (int c = 0; c < 3; ++c) {
        __builtin_amdgcn_global_load_lds(
            (const __attribute__((address_space(1))) void*)(src + row * E_ + c * 256 + ln * 4),
            (__attribute__((address_space(3))) void*)(&xs[row][c * 256]),
            16, 0, 0);
      }
    }
  };

  // ---- prologue: stage tile 0 ----
  stage(0);
  asm volatile("s_waitcnt vmcnt(0)" ::: "memory");
  __syncthreads();

#pragma unroll 1
  for (int t = 0; t < TPB; ++t) {
    const size_t rowg0 = (size_t)(blockIdx.x * TPB + t) * TILE_M;

    // ---- gate GEMM partial (wave wv: K-steps [6wv,6wv+6)); al/pl extracted inline ----
    f32x4 accg = {0.f, 0.f, 0.f, 0.f};
#pragma unroll
    for (int i = 0; i < 6; ++i) {
      const int ks = wv * 6 + i;
      const float4 u0 = *reinterpret_cast<const float4*>(&xs[l15][ks * 32 + kg * 8]);
      const float4 u1 = *reinterpret_cast<const float4*>(&xs[l15][ks * 32 + kg * 8 + 4]);
      short2 lv;
      lv.x = f2bf(u0.x);
      lv.y = f2bf(u1.x);
      *reinterpret_cast<short2*>(&al[l15 * S_AL + 8 * ks + 2 * kg]) = lv;
      short4 pv;
      pv.x = f2bf(0.5f * (u0.x + u0.y));
      pv.y = f2bf(0.5f * (u0.z + u0.w));
      pv.z = f2bf(0.5f * (u1.x + u1.y));
      pv.w = f2bf(0.5f * (u1.z + u1.w));
      *reinterpret_cast<short4*>(&pl[l15 * S_PL + ks * 16 + kg * 4]) = pv;
      const bf16x8 a = { lv.x, f2bf(u0.y), f2bf(u0.z), f2bf(u0.w),
                         lv.y, f2bf(u1.y), f2bf(u1.z), f2bf(u1.w) };
      bf16x8 b;
      if constexpr (USE_WS) {
        b = *reinterpret_cast<const bf16x8*>(&wsG[(ks * 64 + ln) * 8]);
      } else {
#pragma unroll
        for (int j = 0; j < 8; ++j) b[j] = f2bf(w_g1[(ks * 32 + kg * 8 + j) * HID_ + l15]);
      }
      accg = __builtin_amdgcn_mfma_f32_16x16x32_bf16(a, b, accg, 0, 0, 0);
    }
#pragma unroll
    for (int r = 0; r < 4; ++r) red2[wv][kg * 4 + r][l15] = accg[r];

    __syncthreads();   // B1: xs consumed; al/pl/red2 visible

    f32x4 acc[6];
#pragma unroll
    for (int j = 0; j < 6; ++j) acc[j] = (f32x4){0.f, 0.f, 0.f, 0.f};

    if constexpr (USE_WS) {
      // ---- burst: ALL 36 wsL frag loads first, THEN the 12 stage loads ----
      bf16x8 fg[36];
#pragma unroll
      for (int ks = 0; ks < 6; ++ks)
#pragma unroll
        for (int j = 0; j < 6; ++j)
          gload_frag(fg[ks * 6 + j], wlp + (j * 6 + ks) * 512);
      __builtin_amdgcn_sched_barrier(0);
      // Always issue the stage (clamped) so the vmcnt ladder counts are the same
      // in EVERY iteration; last tile re-stages itself (L2-hot, xs is dead).
      stage(t + 1 < TPB ? t + 1 : t);
      __builtin_amdgcn_sched_barrier(0);

      // ---- gate finalize under the L2 latency of group 0 ----
      float gf[4];
#pragma unroll
      for (int r = 0; r < 4; ++r) {
        const int row = kg * 4 + r;
        const float y = red2[0][row][l15] + red2[1][row][l15] +
                        red2[2][row][l15] + red2[3][row][l15] + bg;
        float s = y, q = y * y;
#pragma unroll
        for (int m = 1; m < 16; m <<= 1) {
          s += __shfl_xor(s, m);
          q += __shfl_xor(q, m);
        }
        const float mean = s * (1.f / 16.f);
        const float var  = q * (1.f / 16.f) - mean * mean;
        const float rstd = rsqrtf(var + 1e-5f);
        const float vn = (y - mean) * rstd * lgw + lgb;
        float ps = gelu(vn) * wg2;
#pragma unroll
        for (int m = 1; m < 16; m <<= 1) ps += __shfl_xor(ps, m);
        gf[r] = ps + bg2;
      }

      // ---- ladder: each group waits ONLY its frags; stage rides behind ----
      bf16x8 aLc = *reinterpret_cast<const bf16x8*>(&al[l15 * S_AL + kg * 8]);
      bf16x8 aLn = *reinterpret_cast<const bf16x8*>(&al[l15 * S_AL + 32 + kg * 8]);
      WAITV(42);
#pragma unroll
      for (int j = 0; j < 6; ++j)
        acc[j] = __builtin_amdgcn_mfma_f32_16x16x32_bf16(aLc, fg[0 * 6 + j], acc[j], 0, 0, 0);
      aLc = aLn; aLn = *reinterpret_cast<const bf16x8*>(&al[l15 * S_AL + 64 + kg * 8]);
      WAITV(36);
#pragma unroll
      for (int j = 0; j < 6; ++j)
        acc[j] = __builtin_amdgcn_mfma_f32_16x16x32_bf16(aLc, fg[1 * 6 + j], acc[j], 0, 0, 0);
      aLc = aLn; aLn = *reinterpret_cast<const bf16x8*>(&al[l15 * S_AL + 96 + kg * 8]);
      WAITV(30);
#pragma unroll
      for (int j = 0; j < 6; ++j)
        acc[j] = __builtin_amdgcn_mfma_f32_16x16x32_bf16(aLc, fg[2 * 6 + j], acc[j], 0, 0, 0);
      aLc = aLn; aLn = *reinterpret_cast<const bf16x8*>(&al[l15 * S_AL + 128 + kg * 8]);
      WAITV(24);
#pragma unroll
      for (int j = 0; j < 6; ++j)
        acc[j] = __builtin_amdgcn_mfma_f32_16x16x32_bf16(aLc, fg[3 * 6 + j], acc[j], 0, 0, 0);
      aLc = aLn; aLn = *reinterpret_cast<const bf16x8*>(&al[l15 * S_AL + 160 + kg * 8]);
      WAITV(18);
#pragma unroll
      for (int j = 0; j < 6; ++j)
        acc[j] = __builtin_amdgcn_mfma_f32_16x16x32_bf16(aLc, fg[4 * 6 + j], acc[j], 0, 0, 0);
      aLc = aLn;
      WAITV(12);
#pragma unroll
      for (int j = 0; j < 6; ++j)
        acc[j] = __builtin_amdgcn_mfma_f32_16x16x32_bf16(aLc, fg[5 * 6 + j], acc[j], 0, 0, 0);
      WAITV(0);   // stage drained here (HBM stream rode behind the whole GEMM)

      // ---- LN stats + cross-wave combine ----
      float s1[4] = {0.f, 0.f, 0.f, 0.f}, s2[4] = {0.f, 0.f, 0.f, 0.f};
#pragma unroll
      for (int j = 0; j < 6; ++j) {
#pragma unroll
        for (int r = 0; r < 4; ++r) {
          const float v = acc[j][r] + blv[j];
          acc[j][r] = v;
          s1[r] += v;
          s2[r] += v * v;
        }
      }
#pragma unroll
      for (int m = 1; m < 16; m <<= 1) {
#pragma unroll
        for (int r = 0; r < 4; ++r) {
          s1[r] += __shfl_xor(s1[r], m);
          s2[r] += __shfl_xor(s2[r], m);
        }
      }
      if (l15 == 0) {
#pragma unroll
        for (int r = 0; r < 4; ++r) {
          reds[wv][kg * 4 + r][0] = s1[r];
          reds[wv][kg * 4 + r][1] = s2[r];
        }
      }
      __syncthreads();   // B2

      float meanr[4], rstdr[4];
#pragma unroll
      for (int r = 0; r < 4; ++r) {
        const int row = kg * 4 + r;
        const float t1 = reds[0][row][0] + reds[1][row][0] + reds[2][row][0] + reds[3][row][0];
        const float t2 = reds[0][row][1] + reds[1][row][1] + reds[2][row][1] + reds[3][row][1];
        meanr[r] = t1 * (1.f / 384.f);
        const float var = t2 * (1.f / 384.f) - meanr[r] * meanr[r];
        rstdr[r] = rsqrtf(var + 1e-5f);
      }
#pragma unroll
      for (int j = 0; j < 6; ++j) {
        const int col = (wv * 6 + j) * 16 + l15;
#pragma unroll
        for (int r = 0; r < 4; ++r) {
          const int row = kg * 4 + r;
          const float pooled = bf2f(pl[row * S_PL + col]);
          const float vn = (acc[j][r] - meanr[r]) * rstdr[r] * lwv[j] + lbv[j];
          out[(rowg0 + row) * OUT_ + col] = gelu(vn) + gf[r] + pooled;
        }
      }
      __syncthreads();   // B3: al/pl consumed

    } else {
      // fallback (no workspace): simple serial version
      if (t + 1 < TPB) stage(t + 1);
      float gf[4];
#pragma unroll
      for (int r = 0; r < 4; ++r) {
        const int row = kg * 4 + r;
        const float y = red2[0][row][l15] + red2[1][row][l15] +
                        red2[2][row][l15] + red2[3][row][l15] + bg;
        float s = y, q = y * y;
#pragma unroll
        for (int m = 1; m < 16; m <<= 1) { s += __shfl_xor(s, m); q += __shfl_xor(q, m); }
        const float mean = s * (1.f / 16.f);
        const float var  = q * (1.f / 16.f) - mean * mean;
        const float rstd = rsqrtf(var + 1e-5f);
        const float vn = (y - mean) * rstd * lgw + lgb;
        float ps = gelu(vn) * wg2;
#pragma unroll
        for (int m = 1; m < 16; m <<= 1) ps += __shfl_xor(ps, m);
        gf[r] = ps + bg2;
      }
#pragma unroll
      for (int ks = 0; ks < KT_L; ++ks) {
        const bf16x8 aL = *reinterpret_cast<const bf16x8*>(&al[l15 * S_AL + ks * 32 + kg * 8]);
#pragma unroll
        for (int j = 0; j < 6; ++j) {
          const int ng = wv * 6 + j;
          bf16x8 b;
#pragma unroll
          for (int jj = 0; jj < 8; ++jj)
            b[jj] = f2bf(w_l[(ks * 32 + kg * 8 + jj) * OUT_ + ng * 16 + l15]);
          acc[j] = __builtin_amdgcn_mfma_f32_16x16x32_bf16(aL, b, acc[j], 0, 0, 0);
        }
      }
      asm volatile("s_waitcnt vmcnt(0)" ::: "memory");
      __builtin_amdgcn_sched_barrier(0);
      float s1[4] = {0.f, 0.f, 0.f, 0.f}, s2[4] = {0.f, 0.f, 0.f, 0.f};
#pragma unroll
      for (int j = 0; j < 6; ++j) {
#pragma unroll
        for (int r = 0; r < 4; ++r) {
          const float v = acc[j][r] + blv[j];
          acc[j][r] = v;
          s1[r] += v;
          s2[r] += v * v;
        }
      }
#pragma unroll
      for (int m = 1; m < 16; m <<= 1) {
#pragma unroll
        for (int r = 0; r < 4; ++r) {
          s1[r] += __shfl_xor(s1[r], m);
          s2[r] += __shfl_xor(s2[r], m);
        }
      }
      if (l15 == 0) {
#pragma unroll
        for (int r = 0; r < 4; ++r) {
          reds[wv][kg * 4 + r][0] = s1[r];
          reds[wv][kg * 4 + r][1] = s2[r];
        }
      }
      __syncthreads();
      float meanr[4], rstdr[4];
#pragma unroll
      for (int r = 0; r < 4; ++r) {
        const int row = kg * 4 + r;
        const float t1 = reds[0][row][0] + reds[1][row][0] + reds[2][row][0] + reds[3][row][0];
        const float t2 = reds[0][row][1] + reds[1][row][1] + reds[2][row][1] + reds[3][row][1];
        meanr[r] = t1 * (1.f / 384.f);
        const float var = t2 * (1.f / 384.f) - meanr[r] * meanr[r];
        rstdr[r] = rsqrtf(var + 1e-5f);
      }
#pragma unroll
      for (int j = 0; j < 6; ++j) {
        const int col = (wv * 6 + j) * 16 + l15;
#pragma unroll
        for (int r = 0; r < 4; ++r) {
          const int row = kg * 4 + r;
          const float pooled = bf2f(pl[row * S_PL + col]);
          const float vn = (acc[j][r] - meanr[r]) * rstdr[r] * lwv[j] + lbv[j];
          out[(rowg0 + row) * OUT_ + col] = gelu(vn) + gf[r] + pooled;
        }
      }
      __syncthreads();
    }
  }
}

// ---------------- launch ----------------
extern "C" void kernel_launch(void* const* d_in, const int* in_sizes, int n_in,
                              void* d_out, int out_size, void* d_ws, size_t ws_size,
                              hipStream_t stream) {
  (void)in_sizes; (void)n_in; (void)out_size;
  const float* x      = (const float*)d_in[0];
  const float* w_g1   = (const float*)d_in[1];
  const float* b_g1   = (const float*)d_in[2];
  const float* ln_g_w = (const float*)d_in[3];
  const float* ln_g_b = (const float*)d_in[4];
  const float* w_g2   = (const float*)d_in[5];
  const float* b_g2   = (const float*)d_in[6];
  const float* w_l    = (const float*)d_in[7];
  const float* b_l    = (const float*)d_in[8];
  const float* ln_l_w = (const float*)d_in[9];
  const float* ln_l_b = (const float*)d_in[10];
  float* out = (float*)d_out;

  const size_t needL = (size_t)NT * KT_L * 64 * 8;   // shorts
  const size_t needG = (size_t)KT_G * 64 * 8;        // shorts
  const bool use_ws = ws_size >= (needL + needG) * sizeof(short);

  short* wsL = (short*)d_ws;
  short* wsG = wsL + needL;

  const int grid = ROWS / (TILE_M * TPB);   // 512
  if (use_ws) {
    prep_kernel<<<(NT * KT_L + KT_G) * 64 / 256, 256, 0, stream>>>(w_l, w_g1, wsL, wsG);
    spectre_kernel<true><<<grid, 256, 0, stream>>>(x, w_g1, b_g1, ln_g_w, ln_g_b, w_g2, b_g2,
                                                   w_l, b_l, ln_l_w, ln_l_b, wsL, wsG, out);
  } else {
    spectre_kernel<false><<<grid, 256, 0, stream>>>(x, w_g1, b_g1, ln_g_w, ln_g_b, w_g2, b_g2,
                                                    w_l, b_l, ln_l_w, ln_l_b, nullptr, nullptr, out);
  }
}

// Round 17
// 100.311 us; speedup vs baseline: 1.8274x; 1.1361x over previous
//
#include <hip/hip_runtime.h>
#include <hip/hip_bf16.h>

// Problem constants
#define B_   32
#define N_   2048
#define E_   768
#define OUT_ 384
#define HID_ 16
constexpr int ROWS   = B_ * N_;      // 65536
constexpr int TILE_M = 16;           // rows per block
constexpr int NT     = OUT_ / 16;    // 24 N-tiles of local GEMM
constexpr int KT_L   = 6;            // 6 K-steps (local, K=192)
constexpr int KT_G   = 24;           // 24 K-steps (gate, K=768)
constexpr int S_AL   = 194;          // al row stride in shorts

typedef __attribute__((ext_vector_type(8))) short bf16x8;
typedef __attribute__((ext_vector_type(4))) float f32x4;

__device__ __forceinline__ short f2bf(float f) {
  __hip_bfloat16 h = __float2bfloat16(f);          // RNE hardware cvt
  return __builtin_bit_cast(short, h);
}

// deep async loads: issued where placed, cannot be sunk by the compiler
__device__ __forceinline__ void gload_pair(f32x4& d0, f32x4& d1, const float* a) {
  asm volatile("global_load_dwordx4 %0, %2, off\n\t"
               "global_load_dwordx4 %1, %2, off offset:16"
               : "=&v"(d0), "=&v"(d1)
               : "v"(a));
}
__device__ __forceinline__ void gload_frag(bf16x8& d, const short* a) {
  asm volatile("global_load_dwordx4 %0, %1, off" : "=&v"(d) : "v"(a));
}
#define WAITV(n) do { asm volatile("s_waitcnt vmcnt(" #n ")" ::: "memory"); \
                      __builtin_amdgcn_sched_barrier(0); } while (0)

// Abramowitz-Stegun 7.1.26, |err| <= 1.5e-7, branch-free
__device__ __forceinline__ float fast_erf(float x) {
  const float ax = __builtin_fabsf(x);
  const float t  = __builtin_amdgcn_rcpf(__builtin_fmaf(0.3275911f, ax, 1.0f));
  float p = __builtin_fmaf(1.061405429f, t, -1.453152027f);
  p = __builtin_fmaf(p, t, 1.421413741f);
  p = __builtin_fmaf(p, t, -0.284496736f);
  p = __builtin_fmaf(p, t, 0.254829592f);
  const float e = __expf(-ax * ax);
  const float y = __builtin_fmaf(-p * t, e, 1.0f);
  return __builtin_copysignf(y, x);
}
__device__ __forceinline__ float gelu(float v) {
  return 0.5f * v * (1.0f + fast_erf(v * 0.70710678118654752f));
}

// ---------------- pre-pass: build bf16 MFMA B-fragments in workspace ----------------
__global__ void prep_kernel(const float* __restrict__ w_l, const float* __restrict__ w_g1,
                            short* __restrict__ wsL, short* __restrict__ wsG) {
  int t = blockIdx.x * blockDim.x + threadIdx.x;
  int wave = t >> 6, ln = t & 63;
  int kg = ln >> 4, c16 = ln & 15;
  if (wave < NT * KT_L) {
    int n = wave / KT_L, ks = wave % KT_L;
    bf16x8 v;
#pragma unroll
    for (int j = 0; j < 8; ++j) {
      int k = ks * 32 + kg * 8 + j;
      v[j] = f2bf(w_l[k * OUT_ + n * 16 + c16]);
    }
    *reinterpret_cast<bf16x8*>(&wsL[(size_t)(wave * 64 + ln) * 8]) = v;
  } else if (wave < NT * KT_L + KT_G) {
    int ks = wave - NT * KT_L;
    bf16x8 v;
#pragma unroll
    for (int j = 0; j < 8; ++j) {
      int k = ks * 32 + kg * 8 + j;
      v[j] = f2bf(w_g1[k * HID_ + c16]);
    }
    *reinterpret_cast<bf16x8*>(&wsG[(size_t)(ks * 64 + ln) * 8]) = v;
  }
}

// ---------------- main fused kernel: 128 threads = 2 waves own 16 rows ----------------
// R12 structure (best: 91us) with the pl LDS stash removed -> 9KB LDS for block residency.
template <bool USE_WS>
__global__ __launch_bounds__(128, 2)
void spectre_kernel(const float* __restrict__ x,
                    const float* __restrict__ w_g1, const float* __restrict__ b_g1,
                    const float* __restrict__ ln_g_w, const float* __restrict__ ln_g_b,
                    const float* __restrict__ w_g2, const float* __restrict__ b_g2,
                    const float* __restrict__ w_l, const float* __restrict__ b_l,
                    const float* __restrict__ ln_l_w, const float* __restrict__ ln_l_b,
                    const short* __restrict__ wsL, const short* __restrict__ wsG,
                    float* __restrict__ out) {
  __shared__ short al[TILE_M * S_AL];    // 6208 B: local A (x[..., ::4] bf16), [row][local_k]
  __shared__ float red2[2][16][17];      // 2176 B: gate partial sums per wave
  __shared__ float reds[2][16][2];       // 256 B : local LN partials per wave

  const int tid = threadIdx.x;
  const int wv  = tid >> 6;        // wave 0..1
  const int ln  = tid & 63;        // lane
  const int kg  = ln >> 4;         // k-group / D-row group
  const int l15 = ln & 15;         // A-row / D-col
  const int row0 = blockIdx.x * TILE_M;

  const float* xb = x + (size_t)row0 * E_;

  // ---- gate GEMM partial (wave wv: K-steps [12wv,12wv+12)), asm burst ----
  f32x4 accg = {0.f, 0.f, 0.f, 0.f};
  if constexpr (USE_WS) {
    bf16x8 gbv[12];
#pragma unroll
    for (int i = 0; i < 12; ++i)
      gbv[i] = *reinterpret_cast<const bf16x8*>(&wsG[((wv * 12 + i) * 64 + ln) * 8]);

    asm volatile("s_waitcnt vmcnt(0)" ::: "memory");   // drain compiler vmem
    __builtin_amdgcn_sched_barrier(0);

    f32x4 xa0[6], xa1[6], xb0[6], xb1[6];
    const float* pA = xb + l15 * E_ + kg * 8;
#pragma unroll
    for (int i = 0; i < 6; ++i) gload_pair(xa0[i], xa1[i], pA + (wv * 12 + i) * 32);
#pragma unroll
    for (int i = 0; i < 6; ++i) gload_pair(xb0[i], xb1[i], pA + (wv * 12 + 6 + i) * 32);

    WAITV(12);                                          // batch A (oldest 12) done
#pragma unroll
    for (int i = 0; i < 6; ++i) {
      const int ks = wv * 12 + i;
      const f32x4 u0 = xa0[i], u1 = xa1[i];
      short2 lv;
      lv.x = f2bf(u0[0]);
      lv.y = f2bf(u1[0]);
      *reinterpret_cast<short2*>(&al[l15 * S_AL + 8 * ks + 2 * kg]) = lv;
      const bf16x8 a = { lv.x, f2bf(u0[1]), f2bf(u0[2]), f2bf(u0[3]),
                         lv.y, f2bf(u1[1]), f2bf(u1[2]), f2bf(u1[3]) };
      accg = __builtin_amdgcn_mfma_f32_16x16x32_bf16(a, gbv[i], accg, 0, 0, 0);
    }
    WAITV(0);                                           // batch B done
#pragma unroll
    for (int i = 0; i < 6; ++i) {
      const int ks = wv * 12 + 6 + i;
      const f32x4 u0 = xb0[i], u1 = xb1[i];
      short2 lv;
      lv.x = f2bf(u0[0]);
      lv.y = f2bf(u1[0]);
      *reinterpret_cast<short2*>(&al[l15 * S_AL + 8 * ks + 2 * kg]) = lv;
      const bf16x8 a = { lv.x, f2bf(u0[1]), f2bf(u0[2]), f2bf(u0[3]),
                         lv.y, f2bf(u1[1]), f2bf(u1[2]), f2bf(u1[3]) };
      accg = __builtin_amdgcn_mfma_f32_16x16x32_bf16(a, gbv[6 + i], accg, 0, 0, 0);
    }
    __builtin_amdgcn_sched_barrier(0);
  } else {
    const float* pA = xb + l15 * E_ + kg * 8;
#pragma unroll
    for (int i = 0; i < 12; ++i) {
      const int ks = wv * 12 + i;
      const float4 u0 = *reinterpret_cast<const float4*>(pA + ks * 32);
      const float4 u1 = *reinterpret_cast<const float4*>(pA + ks * 32 + 4);
      short2 lv;
      lv.x = f2bf(u0.x);
      lv.y = f2bf(u1.x);
      *reinterpret_cast<short2*>(&al[l15 * S_AL + 8 * ks + 2 * kg]) = lv;
      bf16x8 b;
#pragma unroll
      for (int j = 0; j < 8; ++j) b[j] = f2bf(w_g1[(ks * 32 + kg * 8 + j) * HID_ + l15]);
      const bf16x8 a = { lv.x, f2bf(u0.y), f2bf(u0.z), f2bf(u0.w),
                         lv.y, f2bf(u1.y), f2bf(u1.z), f2bf(u1.w) };
      accg = __builtin_amdgcn_mfma_f32_16x16x32_bf16(a, b, accg, 0, 0, 0);
    }
  }
#pragma unroll
  for (int r = 0; r < 4; ++r) red2[wv][kg * 4 + r][l15] = accg[r];

  // hoist per-lane constants (latency hidden under barrier + local GEMM)
  const float bg  = b_g1[l15];
  const float lgw = ln_g_w[l15];
  const float lgb = ln_g_b[l15];
  const float wg2 = w_g2[l15];
  const float bg2 = b_g2[0];
  float blv[12];
#pragma unroll
  for (int n = 0; n < 12; ++n) blv[n] = b_l[(wv * 12 + n) * 16 + l15];

  __syncthreads();   // al + red2 visible

  // ---- local A fragments from LDS ----
  bf16x8 aL[KT_L];
#pragma unroll
  for (int ks = 0; ks < KT_L; ++ks)
    aL[ks] = *reinterpret_cast<const bf16x8*>(&al[l15 * S_AL + ks * 32 + kg * 8]);

  // ---- local GEMM ----
  f32x4 acc[12];
#pragma unroll
  for (int n = 0; n < 12; ++n) acc[n] = (f32x4){0.f, 0.f, 0.f, 0.f};

  if constexpr (USE_WS) {
    // deep asm pipeline: two 12-frag groups, 24 loads (24KB) in flight, counted waits
    const short* wlp = wsL + ((size_t)(wv * 12) * KT_L * 64 + ln) * 8;
    bf16x8 fA[12], fB[12];

    asm volatile("s_waitcnt vmcnt(0)" ::: "memory");   // drain stray vmem
    __builtin_amdgcn_sched_barrier(0);
#pragma unroll
    for (int j = 0; j < 12; ++j) gload_frag(fA[j], wlp + (j * 6 + 0) * 512);
#pragma unroll
    for (int j = 0; j < 12; ++j) gload_frag(fB[j], wlp + (j * 6 + 1) * 512);

    WAITV(12);   // ks=0 group done
#pragma unroll
    for (int j = 0; j < 12; ++j)
      acc[j] = __builtin_amdgcn_mfma_f32_16x16x32_bf16(aL[0], fA[j], acc[j], 0, 0, 0);
#pragma unroll
    for (int j = 0; j < 12; ++j) gload_frag(fA[j], wlp + (j * 6 + 2) * 512);

    WAITV(12);   // ks=1 group done
#pragma unroll
    for (int j = 0; j < 12; ++j)
      acc[j] = __builtin_amdgcn_mfma_f32_16x16x32_bf16(aL[1], fB[j], acc[j], 0, 0, 0);
#pragma unroll
    for (int j = 0; j < 12; ++j) gload_frag(fB[j], wlp + (j * 6 + 3) * 512);

    WAITV(12);   // ks=2 group done
#pragma unroll
    for (int j = 0; j < 12; ++j)
      acc[j] = __builtin_amdgcn_mfma_f32_16x16x32_bf16(aL[2], fA[j], acc[j], 0, 0, 0);
#pragma unroll
    for (int j = 0; j < 12; ++j) gload_frag(fA[j], wlp + (j * 6 + 4) * 512);

    WAITV(12);   // ks=3 group done
#pragma unroll
    for (int j = 0; j < 12; ++j)
      acc[j] = __builtin_amdgcn_mfma_f32_16x16x32_bf16(aL[3], fB[j], acc[j], 0, 0, 0);
#pragma unroll
    for (int j = 0; j < 12; ++j) gload_frag(fB[j], wlp + (j * 6 + 5) * 512);

    WAITV(12);   // ks=4 group done
#pragma unroll
    for (int j = 0; j < 12; ++j)
      acc[j] = __builtin_amdgcn_mfma_f32_16x16x32_bf16(aL[4], fA[j], acc[j], 0, 0, 0);

    WAITV(0);    // ks=5 group done
#pragma unroll
    for (int j = 0; j < 12; ++j)
      acc[j] = __builtin_amdgcn_mfma_f32_16x16x32_bf16(aL[5], fB[j], acc[j], 0, 0, 0);
    __builtin_amdgcn_sched_barrier(0);
  } else {
#pragma unroll
    for (int ks = 0; ks < KT_L; ++ks) {
#pragma unroll
      for (int j = 0; j < 12; ++j) {
        const int ng = wv * 12 + j;
        bf16x8 b;
#pragma unroll
        for (int jj = 0; jj < 8; ++jj)
          b[jj] = f2bf(w_l[(ks * 32 + kg * 8 + jj) * OUT_ + ng * 16 + l15]);
        acc[j] = __builtin_amdgcn_mfma_f32_16x16x32_bf16(aL[ks], b, acc[j], 0, 0, 0);
      }
    }
  }

  // ---- add b_l, per-row LN stats over this wave's 192 cols ----
  float s1[4] = {0.f, 0.f, 0.f, 0.f}, s2[4] = {0.f, 0.f, 0.f, 0.f};
#pragma unroll
  for (int n = 0; n < 12; ++n) {
#pragma unroll
    for (int r = 0; r < 4; ++r) {
      const float v = acc[n][r] + blv[n];
      acc[n][r] = v;
      s1[r] += v;
      s2[r] += v * v;
    }
  }
#pragma unroll
  for (int m = 1; m < 16; m <<= 1) {
#pragma unroll
    for (int r = 0; r < 4; ++r) {
      s1[r] += __shfl_xor(s1[r], m);
      s2[r] += __shfl_xor(s2[r], m);
    }
  }
  if (l15 == 0) {
#pragma unroll
    for (int r = 0; r < 4; ++r) {
      reds[wv][kg * 4 + r][0] = s1[r];
      reds[wv][kg * 4 + r][1] = s2[r];
    }
  }
  __syncthreads();

  // hoist LN-local params (latency hidden under gate finalize)
  float lwv[12], lbv[12];
#pragma unroll
  for (int n = 0; n < 12; ++n) {
    const int col = (wv * 12 + n) * 16 + l15;
    lwv[n] = ln_l_w[col];
    lbv[n] = ln_l_b[col];
  }

  // ---- gate finalize: combine wave partials, LN over 16, GeLU, dot w_g2 ----
  float gf[4];
#pragma unroll
  for (int r = 0; r < 4; ++r) {
    const int row = kg * 4 + r;
    const float y = red2[0][row][l15] + red2[1][row][l15] + bg;
    float s = y, q = y * y;
#pragma unroll
    for (int m = 1; m < 16; m <<= 1) {
      s += __shfl_xor(s, m);
      q += __shfl_xor(q, m);
    }
    const float mean = s * (1.f / 16.f);
    const float var  = q * (1.f / 16.f) - mean * mean;
    const float rstd = rsqrtf(var + 1e-5f);
    const float vn = (y - mean) * rstd * lgw + lgb;
    float ps = gelu(vn) * wg2;
#pragma unroll
    for (int m = 1; m < 16; m <<= 1) ps += __shfl_xor(ps, m);
    gf[r] = ps + bg2;
  }

  // ---- local finalize: LN over 384, GeLU, + pooled (global re-read, L2/L3-hot) + gate ----
  float meanr[4], rstdr[4];
#pragma unroll
  for (int r = 0; r < 4; ++r) {
    const int row = kg * 4 + r;
    const float t1 = reds[0][row][0] + reds[1][row][0];
    const float t2 = reds[0][row][1] + reds[1][row][1];
    meanr[r] = t1 * (1.f / 384.f);
    const float var = t2 * (1.f / 384.f) - meanr[r] * meanr[r];
    rstdr[r] = rsqrtf(var + 1e-5f);
  }
#pragma unroll
  for (int n = 0; n < 12; ++n) {
    const int col = (wv * 12 + n) * 16 + l15;
#pragma unroll
    for (int r = 0; r < 4; ++r) {
      const int row = kg * 4 + r;
      const float2 px = *reinterpret_cast<const float2*>(xb + (size_t)row * E_ + 2 * col);
      const float pooled = 0.5f * (px.x + px.y);
      const float vn = (acc[n][r] - meanr[r]) * rstdr[r] * lwv[n] + lbv[n];
      out[(size_t)(row0 + row) * OUT_ + col] = gelu(vn) + gf[r] + pooled;
    }
  }
}

// ---------------- launch ----------------
extern "C" void kernel_launch(void* const* d_in, const int* in_sizes, int n_in,
                              void* d_out, int out_size, void* d_ws, size_t ws_size,
                              hipStream_t stream) {
  (void)in_sizes; (void)n_in; (void)out_size;
  const float* x      = (const float*)d_in[0];
  const float* w_g1   = (const float*)d_in[1];
  const float* b_g1   = (const float*)d_in[2];
  const float* ln_g_w = (const float*)d_in[3];
  const float* ln_g_b = (const float*)d_in[4];
  const float* w_g2   = (const float*)d_in[5];
  const float* b_g2   = (const float*)d_in[6];
  const float* w_l    = (const float*)d_in[7];
  const float* b_l    = (const float*)d_in[8];
  const float* ln_l_w = (const float*)d_in[9];
  const float* ln_l_b = (const float*)d_in[10];
  float* out = (float*)d_out;

  const size_t needL = (size_t)NT * KT_L * 64 * 8;   // shorts
  const size_t needG = (size_t)KT_G * 64 * 8;        // shorts
  const bool use_ws = ws_size >= (needL + needG) * sizeof(short);

  short* wsL = (short*)d_ws;
  short* wsG = wsL + needL;

  const int grid = ROWS / TILE_M;   // 4096
  if (use_ws) {
    prep_kernel<<<(NT * KT_L + KT_G) * 64 / 256, 256, 0, stream>>>(w_l, w_g1, wsL, wsG);
    spectre_kernel<true><<<grid, 128, 0, stream>>>(x, w_g1, b_g1, ln_g_w, ln_g_b, w_g2, b_g2,
                                                   w_l, b_l, ln_l_w, ln_l_b, wsL, wsG, out);
  } else {
    spectre_kernel<false><<<grid, 128, 0, stream>>>(x, w_g1, b_g1, ln_g_w, ln_g_b, w_g2, b_g2,
                                                    w_l, b_l, ln_l_w, ln_l_b, nullptr, nullptr, out);
  }
}

// Round 18
// 88.642 us; speedup vs baseline: 2.0680x; 1.1316x over previous
//
#include <hip/hip_runtime.h>
#include <hip/hip_bf16.h>

// Problem constants
#define B_   32
#define N_   2048
#define E_   768
#define OUT_ 384
#define HID_ 16
constexpr int ROWS   = B_ * N_;      // 65536
constexpr int TILE_M = 32;           // rows per block (2 row-tiles of 16)
constexpr int NT     = OUT_ / 16;    // 24 N-tiles of local GEMM
constexpr int KT_L   = 6;            // 6 K-steps (local, K=192)
constexpr int KT_G   = 24;           // 24 K-steps (gate, K=768)
constexpr int S_AL   = 194;          // al row stride in shorts
constexpr int S_PL   = 392;          // pooled row stride in shorts

typedef __attribute__((ext_vector_type(8))) short bf16x8;
typedef __attribute__((ext_vector_type(4))) float f32x4;

__device__ __forceinline__ short f2bf(float f) {
  __hip_bfloat16 h = __float2bfloat16(f);          // RNE hardware cvt
  return __builtin_bit_cast(short, h);
}
__device__ __forceinline__ float bf2f(short s) {
  union { unsigned u; float f; } v; v.u = ((unsigned)(unsigned short)s) << 16;
  return v.f;
}

// deep async loads: issued where placed, cannot be sunk by the compiler
__device__ __forceinline__ void gload_pair(f32x4& d0, f32x4& d1, const float* a) {
  asm volatile("global_load_dwordx4 %0, %2, off\n\t"
               "global_load_dwordx4 %1, %2, off offset:16"
               : "=&v"(d0), "=&v"(d1)
               : "v"(a));
}
__device__ __forceinline__ void gload_frag(bf16x8& d, const short* a) {
  asm volatile("global_load_dwordx4 %0, %1, off" : "=&v"(d) : "v"(a));
}
#define WAITV(n) do { asm volatile("s_waitcnt vmcnt(" #n ")" ::: "memory"); \
                      __builtin_amdgcn_sched_barrier(0); } while (0)

// Abramowitz-Stegun 7.1.26, |err| <= 1.5e-7, branch-free
__device__ __forceinline__ float fast_erf(float x) {
  const float ax = __builtin_fabsf(x);
  const float t  = __builtin_amdgcn_rcpf(__builtin_fmaf(0.3275911f, ax, 1.0f));
  float p = __builtin_fmaf(1.061405429f, t, -1.453152027f);
  p = __builtin_fmaf(p, t, 1.421413741f);
  p = __builtin_fmaf(p, t, -0.284496736f);
  p = __builtin_fmaf(p, t, 0.254829592f);
  const float e = __expf(-ax * ax);
  const float y = __builtin_fmaf(-p * t, e, 1.0f);
  return __builtin_copysignf(y, x);
}
__device__ __forceinline__ float gelu(float v) {
  return 0.5f * v * (1.0f + fast_erf(v * 0.70710678118654752f));
}

// ---------------- pre-pass: build bf16 MFMA B-fragments in workspace ----------------
__global__ void prep_kernel(const float* __restrict__ w_l, const float* __restrict__ w_g1,
                            short* __restrict__ wsL, short* __restrict__ wsG) {
  int t = blockIdx.x * blockDim.x + threadIdx.x;
  int wave = t >> 6, ln = t & 63;
  int kg = ln >> 4, c16 = ln & 15;
  if (wave < NT * KT_L) {
    int n = wave / KT_L, ks = wave % KT_L;
    bf16x8 v;
#pragma unroll
    for (int j = 0; j < 8; ++j) {
      int k = ks * 32 + kg * 8 + j;
      v[j] = f2bf(w_l[k * OUT_ + n * 16 + c16]);
    }
    *reinterpret_cast<bf16x8*>(&wsL[(size_t)(wave * 64 + ln) * 8]) = v;
  } else if (wave < NT * KT_L + KT_G) {
    int ks = wave - NT * KT_L;
    bf16x8 v;
#pragma unroll
    for (int j = 0; j < 8; ++j) {
      int k = ks * 32 + kg * 8 + j;
      v[j] = f2bf(w_g1[k * HID_ + c16]);
    }
    *reinterpret_cast<bf16x8*>(&wsG[(size_t)(ks * 64 + ln) * 8]) = v;
  }
}

// ---------------- main fused kernel: 256 threads = 4 waves own 32 rows ----------------
// Gate: wave (wvp,wvk) does rows [wvp*16,+16) x K-half wvk (R12 burst). Local GEMM:
// wave wv does n-tiles [wv*6,+6) for BOTH row-tiles -> each B-frag feeds 2 MFMAs.
template <bool USE_WS>
__global__ __launch_bounds__(256, 2)
void spectre_kernel(const float* __restrict__ x,
                    const float* __restrict__ w_g1, const float* __restrict__ b_g1,
                    const float* __restrict__ ln_g_w, const float* __restrict__ ln_g_b,
                    const float* __restrict__ w_g2, const float* __restrict__ b_g2,
                    const float* __restrict__ w_l, const float* __restrict__ b_l,
                    const float* __restrict__ ln_l_w, const float* __restrict__ ln_l_b,
                    const short* __restrict__ wsL, const short* __restrict__ wsG,
                    float* __restrict__ out) {
  __shared__ short al[TILE_M * S_AL];    // 12416 B: local A (x[..., ::4] bf16)
  __shared__ short pl[TILE_M * S_PL];    // 25088 B: pooled (bf16)
  __shared__ float red2[4][16][17];      // 4352 B : gate partials per wave
  __shared__ float reds[4][32][2];       // 1024 B : local LN partials per wave
  __shared__ float gfl[32];              // 128 B  : per-row global feat

  const int tid = threadIdx.x;
  const int wv  = tid >> 6;        // wave 0..3
  const int wvp = wv >> 1;         // row-tile for gate (0: rows 0-15, 1: rows 16-31)
  const int wvk = wv & 1;          // K-half for gate
  const int ln  = tid & 63;
  const int kg  = ln >> 4;
  const int l15 = ln & 15;
  const int row0 = blockIdx.x * TILE_M;

  const float* xb = x + (size_t)(row0 + wvp * 16) * E_;

  // hoisted params (drained before asm regions)
  const float bg  = b_g1[l15];
  const float lgw = ln_g_w[l15];
  const float lgb = ln_g_b[l15];
  const float wg2 = w_g2[l15];
  const float bg2 = b_g2[0];
  float blv[6], lwv[6], lbv[6];
#pragma unroll
  for (int j = 0; j < 6; ++j) {
    const int col = (wv * 6 + j) * 16 + l15;
    blv[j] = b_l[col];
    lwv[j] = ln_l_w[col];
    lbv[j] = ln_l_b[col];
  }

  // ---- gate GEMM partial (rows wvp*16.., K-steps [12wvk,12wvk+12)), asm burst ----
  f32x4 accg = {0.f, 0.f, 0.f, 0.f};
  const int alr = (wvp * 16 + l15);   // al/pl row this lane stages
  if constexpr (USE_WS) {
    bf16x8 gbv[12];
#pragma unroll
    for (int i = 0; i < 12; ++i)
      gbv[i] = *reinterpret_cast<const bf16x8*>(&wsG[((wvk * 12 + i) * 64 + ln) * 8]);

    asm volatile("s_waitcnt vmcnt(0)" ::: "memory");
    __builtin_amdgcn_sched_barrier(0);

    f32x4 xa0[6], xa1[6], xb0[6], xb1[6];
    const float* pA = xb + l15 * E_ + kg * 8;
#pragma unroll
    for (int i = 0; i < 6; ++i) gload_pair(xa0[i], xa1[i], pA + (wvk * 12 + i) * 32);
#pragma unroll
    for (int i = 0; i < 6; ++i) gload_pair(xb0[i], xb1[i], pA + (wvk * 12 + 6 + i) * 32);

    WAITV(12);
#pragma unroll
    for (int i = 0; i < 6; ++i) {
      const int ks = wvk * 12 + i;
      const f32x4 u0 = xa0[i], u1 = xa1[i];
      short2 lv;
      lv.x = f2bf(u0[0]);
      lv.y = f2bf(u1[0]);
      *reinterpret_cast<short2*>(&al[alr * S_AL + 8 * ks + 2 * kg]) = lv;
      short4 pv;
      pv.x = f2bf(0.5f * (u0[0] + u0[1]));
      pv.y = f2bf(0.5f * (u0[2] + u0[3]));
      pv.z = f2bf(0.5f * (u1[0] + u1[1]));
      pv.w = f2bf(0.5f * (u1[2] + u1[3]));
      *reinterpret_cast<short4*>(&pl[alr * S_PL + ks * 16 + kg * 4]) = pv;
      const bf16x8 a = { lv.x, f2bf(u0[1]), f2bf(u0[2]), f2bf(u0[3]),
                         lv.y, f2bf(u1[1]), f2bf(u1[2]), f2bf(u1[3]) };
      accg = __builtin_amdgcn_mfma_f32_16x16x32_bf16(a, gbv[i], accg, 0, 0, 0);
    }
    WAITV(0);
#pragma unroll
    for (int i = 0; i < 6; ++i) {
      const int ks = wvk * 12 + 6 + i;
      const f32x4 u0 = xb0[i], u1 = xb1[i];
      short2 lv;
      lv.x = f2bf(u0[0]);
      lv.y = f2bf(u1[0]);
      *reinterpret_cast<short2*>(&al[alr * S_AL + 8 * ks + 2 * kg]) = lv;
      short4 pv;
      pv.x = f2bf(0.5f * (u0[0] + u0[1]));
      pv.y = f2bf(0.5f * (u0[2] + u0[3]));
      pv.z = f2bf(0.5f * (u1[0] + u1[1]));
      pv.w = f2bf(0.5f * (u1[2] + u1[3]));
      *reinterpret_cast<short4*>(&pl[alr * S_PL + ks * 16 + kg * 4]) = pv;
      const bf16x8 a = { lv.x, f2bf(u0[1]), f2bf(u0[2]), f2bf(u0[3]),
                         lv.y, f2bf(u1[1]), f2bf(u1[2]), f2bf(u1[3]) };
      accg = __builtin_amdgcn_mfma_f32_16x16x32_bf16(a, gbv[6 + i], accg, 0, 0, 0);
    }
    __builtin_amdgcn_sched_barrier(0);
  } else {
    const float* pA = xb + l15 * E_ + kg * 8;
#pragma unroll
    for (int i = 0; i < 12; ++i) {
      const int ks = wvk * 12 + i;
      const float4 u0 = *reinterpret_cast<const float4*>(pA + ks * 32);
      const float4 u1 = *reinterpret_cast<const float4*>(pA + ks * 32 + 4);
      short2 lv;
      lv.x = f2bf(u0.x);
      lv.y = f2bf(u1.x);
      *reinterpret_cast<short2*>(&al[alr * S_AL + 8 * ks + 2 * kg]) = lv;
      short4 pv;
      pv.x = f2bf(0.5f * (u0.x + u0.y));
      pv.y = f2bf(0.5f * (u0.z + u0.w));
      pv.z = f2bf(0.5f * (u1.x + u1.y));
      pv.w = f2bf(0.5f * (u1.z + u1.w));
      *reinterpret_cast<short4*>(&pl[alr * S_PL + ks * 16 + kg * 4]) = pv;
      bf16x8 b;
#pragma unroll
      for (int j = 0; j < 8; ++j) b[j] = f2bf(w_g1[(ks * 32 + kg * 8 + j) * HID_ + l15]);
      const bf16x8 a = { lv.x, f2bf(u0.y), f2bf(u0.z), f2bf(u0.w),
                         lv.y, f2bf(u1.y), f2bf(u1.z), f2bf(u1.w) };
      accg = __builtin_amdgcn_mfma_f32_16x16x32_bf16(a, b, accg, 0, 0, 0);
    }
  }
#pragma unroll
  for (int r = 0; r < 4; ++r) red2[wv][kg * 4 + r][l15] = accg[r];

  __syncthreads();   // B1: al/pl/red2 visible

  // ---- local GEMM: frag reuse across both row-tiles; asm ladder 6 loads / 12 MFMAs ----
  f32x4 acc0[6], acc1[6];
#pragma unroll
  for (int j = 0; j < 6; ++j) {
    acc0[j] = (f32x4){0.f, 0.f, 0.f, 0.f};
    acc1[j] = (f32x4){0.f, 0.f, 0.f, 0.f};
  }

  if constexpr (USE_WS) {
    const short* wlp = wsL + ((size_t)(wv * 6) * KT_L * 64 + ln) * 8;
    bf16x8 fA[6], fB[6];
#pragma unroll
    for (int j = 0; j < 6; ++j) gload_frag(fA[j], wlp + (j * 6 + 0) * 512);
#pragma unroll
    for (int j = 0; j < 6; ++j) gload_frag(fB[j], wlp + (j * 6 + 1) * 512);
    __builtin_amdgcn_sched_barrier(0);

    // gate finalize under the frag-load latency (LDS + VALU only; no vmem)
    float gf[4];
#pragma unroll
    for (int r = 0; r < 4; ++r) {
      const int row = kg * 4 + r;
      const float y = red2[2 * wvp][row][l15] + red2[2 * wvp + 1][row][l15] + bg;
      float s = y, q = y * y;
#pragma unroll
      for (int m = 1; m < 16; m <<= 1) {
        s += __shfl_xor(s, m);
        q += __shfl_xor(q, m);
      }
      const float mean = s * (1.f / 16.f);
      const float var  = q * (1.f / 16.f) - mean * mean;
      const float rstd = rsqrtf(var + 1e-5f);
      const float vn = (y - mean) * rstd * lgw + lgb;
      float ps = gelu(vn) * wg2;
#pragma unroll
      for (int m = 1; m < 16; m <<= 1) ps += __shfl_xor(ps, m);
      gf[r] = ps + bg2;
    }
    if (wvk == 0 && l15 == 0) {
#pragma unroll
      for (int r = 0; r < 4; ++r) gfl[wvp * 16 + kg * 4 + r] = gf[r];
    }

#define LKSTEP(KS, FREG, NEXTKS, NEXTREG, LASTWAIT)                                   \
    do {                                                                              \
      WAITV(LASTWAIT);                                                                \
      const bf16x8 aL0 = *reinterpret_cast<const bf16x8*>(                            \
          &al[l15 * S_AL + (KS) * 32 + kg * 8]);                                      \
      const bf16x8 aL1 = *reinterpret_cast<const bf16x8*>(                            \
          &al[(16 + l15) * S_AL + (KS) * 32 + kg * 8]);                               \
      _Pragma("unroll")                                                               \
      for (int j = 0; j < 6; ++j) {                                                   \
        acc0[j] = __builtin_amdgcn_mfma_f32_16x16x32_bf16(aL0, FREG[j], acc0[j], 0, 0, 0); \
        acc1[j] = __builtin_amdgcn_mfma_f32_16x16x32_bf16(aL1, FREG[j], acc1[j], 0, 0, 0); \
      }                                                                               \
      if ((NEXTKS) < KT_L) {                                                          \
        _Pragma("unroll")                                                             \
        for (int j = 0; j < 6; ++j)                                                   \
          gload_frag(NEXTREG[j], wlp + (j * 6 + (NEXTKS)) * 512);                     \
      }                                                                               \
    } while (0)

    LKSTEP(0, fA, 2, fA, 6);
    LKSTEP(1, fB, 3, fB, 6);
    LKSTEP(2, fA, 4, fA, 6);
    LKSTEP(3, fB, 5, fB, 6);
    LKSTEP(4, fA, 6, fA, 6);
    LKSTEP(5, fB, 6, fB, 0);
#undef LKSTEP
    __builtin_amdgcn_sched_barrier(0);
  } else {
    // gate finalize
    float gf[4];
#pragma unroll
    for (int r = 0; r < 4; ++r) {
      const int row = kg * 4 + r;
      const float y = red2[2 * wvp][row][l15] + red2[2 * wvp + 1][row][l15] + bg;
      float s = y, q = y * y;
#pragma unroll
      for (int m = 1; m < 16; m <<= 1) { s += __shfl_xor(s, m); q += __shfl_xor(q, m); }
      const float mean = s * (1.f / 16.f);
      const float var  = q * (1.f / 16.f) - mean * mean;
      const float rstd = rsqrtf(var + 1e-5f);
      const float vn = (y - mean) * rstd * lgw + lgb;
      float ps = gelu(vn) * wg2;
#pragma unroll
      for (int m = 1; m < 16; m <<= 1) ps += __shfl_xor(ps, m);
      gf[r] = ps + bg2;
    }
    if (wvk == 0 && l15 == 0) {
#pragma unroll
      for (int r = 0; r < 4; ++r) gfl[wvp * 16 + kg * 4 + r] = gf[r];
    }
#pragma unroll
    for (int ks = 0; ks < KT_L; ++ks) {
      const bf16x8 aL0 = *reinterpret_cast<const bf16x8*>(&al[l15 * S_AL + ks * 32 + kg * 8]);
      const bf16x8 aL1 = *reinterpret_cast<const bf16x8*>(&al[(16 + l15) * S_AL + ks * 32 + kg * 8]);
#pragma unroll
      for (int j = 0; j < 6; ++j) {
        const int ng = wv * 6 + j;
        bf16x8 b;
#pragma unroll
        for (int jj = 0; jj < 8; ++jj)
          b[jj] = f2bf(w_l[(ks * 32 + kg * 8 + jj) * OUT_ + ng * 16 + l15]);
        acc0[j] = __builtin_amdgcn_mfma_f32_16x16x32_bf16(aL0, b, acc0[j], 0, 0, 0);
        acc1[j] = __builtin_amdgcn_mfma_f32_16x16x32_bf16(aL1, b, acc1[j], 0, 0, 0);
      }
    }
  }

  // ---- add b_l, LN stats over this wave's 96 cols for BOTH row-tiles ----
  float s10[4] = {0.f, 0.f, 0.f, 0.f}, s20[4] = {0.f, 0.f, 0.f, 0.f};
  float s11[4] = {0.f, 0.f, 0.f, 0.f}, s21[4] = {0.f, 0.f, 0.f, 0.f};
#pragma unroll
  for (int j = 0; j < 6; ++j) {
#pragma unroll
    for (int r = 0; r < 4; ++r) {
      const float v0 = acc0[j][r] + blv[j];
      acc0[j][r] = v0;
      s10[r] += v0; s20[r] += v0 * v0;
      const float v1 = acc1[j][r] + blv[j];
      acc1[j][r] = v1;
      s11[r] += v1; s21[r] += v1 * v1;
    }
  }
#pragma unroll
  for (int m = 1; m < 16; m <<= 1) {
#pragma unroll
    for (int r = 0; r < 4; ++r) {
      s10[r] += __shfl_xor(s10[r], m);
      s20[r] += __shfl_xor(s20[r], m);
      s11[r] += __shfl_xor(s11[r], m);
      s21[r] += __shfl_xor(s21[r], m);
    }
  }
  if (l15 == 0) {
#pragma unroll
    for (int r = 0; r < 4; ++r) {
      reds[wv][kg * 4 + r][0] = s10[r];
      reds[wv][kg * 4 + r][1] = s20[r];
      reds[wv][16 + kg * 4 + r][0] = s11[r];
      reds[wv][16 + kg * 4 + r][1] = s21[r];
    }
  }
  __syncthreads();   // B2: reds + gfl visible

  // ---- local finalize: LN over 384 (4-wave combine), GeLU, + pooled + gate; store ----
  float mean0[4], rstd0[4], mean1[4], rstd1[4];
#pragma unroll
  for (int r = 0; r < 4; ++r) {
    const int row = kg * 4 + r;
    float t1 = reds[0][row][0] + reds[1][row][0] + reds[2][row][0] + reds[3][row][0];
    float t2 = reds[0][row][1] + reds[1][row][1] + reds[2][row][1] + reds[3][row][1];
    mean0[r] = t1 * (1.f / 384.f);
    rstd0[r] = rsqrtf(t2 * (1.f / 384.f) - mean0[r] * mean0[r] + 1e-5f);
    t1 = reds[0][16 + row][0] + reds[1][16 + row][0] + reds[2][16 + row][0] + reds[3][16 + row][0];
    t2 = reds[0][16 + row][1] + reds[1][16 + row][1] + reds[2][16 + row][1] + reds[3][16 + row][1];
    mean1[r] = t1 * (1.f / 384.f);
    rstd1[r] = rsqrtf(t2 * (1.f / 384.f) - mean1[r] * mean1[r] + 1e-5f);
  }
#pragma unroll
  for (int n = 0; n < 6; ++n) {
    const int col = (wv * 6 + n) * 16 + l15;
#pragma unroll
    for (int r = 0; r < 4; ++r) {
      const int rowA = kg * 4 + r;
      {
        const float pooled = bf2f(pl[rowA * S_PL + col]);
        const float vn = (acc0[n][r] - mean0[r]) * rstd0[r] * lwv[n] + lbv[n];
        out[(size_t)(row0 + rowA) * OUT_ + col] = gelu(vn) + gfl[rowA] + pooled;
      }
      {
        const int rowB = 16 + rowA;
        const float pooled = bf2f(pl[rowB * S_PL + col]);
        const float vn = (acc1[n][r] - mean1[r]) * rstd1[r] * lwv[n] + lbv[n];
        out[(size_t)(row0 + rowB) * OUT_ + col] = gelu(vn) + gfl[rowB] + pooled;
      }
    }
  }
}

// ---------------- launch ----------------
extern "C" void kernel_launch(void* const* d_in, const int* in_sizes, int n_in,
                              void* d_out, int out_size, void* d_ws, size_t ws_size,
                              hipStream_t stream) {
  (void)in_sizes; (void)n_in; (void)out_size;
  const float* x      = (const float*)d_in[0];
  const float* w_g1   = (const float*)d_in[1];
  const float* b_g1   = (const float*)d_in[2];
  const float* ln_g_w = (const float*)d_in[3];
  const float* ln_g_b = (const float*)d_in[4];
  const float* w_g2   = (const float*)d_in[5];
  const float* b_g2   = (const float*)d_in[6];
  const float* w_l    = (const float*)d_in[7];
  const float* b_l    = (const float*)d_in[8];
  const float* ln_l_w = (const float*)d_in[9];
  const float* ln_l_b = (const float*)d_in[10];
  float* out = (float*)d_out;

  const size_t needL = (size_t)NT * KT_L * 64 * 8;   // shorts
  const size_t needG = (size_t)KT_G * 64 * 8;        // shorts
  const bool use_ws = ws_size >= (needL + needG) * sizeof(short);

  short* wsL = (short*)d_ws;
  short* wsG = wsL + needL;

  const int grid = ROWS / TILE_M;   // 2048
  if (use_ws) {
    prep_kernel<<<(NT * KT_L + KT_G) * 64 / 256, 256, 0, stream>>>(w_l, w_g1, wsL, wsG);
    spectre_kernel<true><<<grid, 256, 0, stream>>>(x, w_g1, b_g1, ln_g_w, ln_g_b, w_g2, b_g2,
                                                   w_l, b_l, ln_l_w, ln_l_b, wsL, wsG, out);
  } else {
    spectre_kernel<false><<<grid, 256, 0, stream>>>(x, w_g1, b_g1, ln_g_w, ln_g_b, w_g2, b_g2,
                                                    w_l, b_l, ln_l_w, ln_l_b, nullptr, nullptr, out);
  }
}